// Round 3
// baseline (2394.717 us; speedup 1.0000x reference)
//
#include <hip/hip_runtime.h>

#define DEV __device__ __forceinline__

typedef unsigned short u16;
using bf16x8 = __attribute__((ext_vector_type(8))) __bf16;
using f32x4  = __attribute__((ext_vector_type(4))) float;

DEV u16 f2bf(float f){
  unsigned u = __float_as_uint(f);
  u += 0x7fffu + ((u >> 16) & 1u);   // round-to-nearest-even
  return (u16)(u >> 16);
}
DEV float sigf(float x){ return 1.f / (1.f + __expf(-x)); }
DEV float tanh_(float x){ return 2.f / (1.f + __expf(-2.f*x)) - 1.f; } // safe at +/-inf

DEV void async16(const u16* g, u16* l){
  __builtin_amdgcn_global_load_lds(
      (const __attribute__((address_space(1))) unsigned int*)g,
      (__attribute__((address_space(3))) unsigned int*)l, 16, 0, 0);
}

// ---------------- BatchNorm (training-mode batch stats, biased var) ----------
__global__ void bn_stats(const float* __restrict__ z, float* __restrict__ ps, float* __restrict__ pq){
  int bx = blockIdx.x; int rg = bx >> 2, cg = bx & 3;
  int c = cg*256 + threadIdx.x;
  float s = 0.f, q = 0.f;
  for (int r = rg*64; r < rg*64 + 64; ++r){ float v = z[r*1024 + c]; s += v; q += v*v; }
  ps[rg*1024 + c] = s; pq[rg*1024 + c] = q;
}

__global__ void bn_fin(const float* __restrict__ ps, const float* __restrict__ pq,
                       const float* __restrict__ gam, const float* __restrict__ bet,
                       float* __restrict__ sc, float* __restrict__ sh){
  int c = blockIdx.x*256 + threadIdx.x;
  float s = 0.f, q = 0.f;
  for (int rg = 0; rg < 16; ++rg){ s += ps[rg*1024 + c]; q += pq[rg*1024 + c]; }
  float mean = s * (1.f/1024.f);
  float var  = q * (1.f/1024.f) - mean*mean;
  float k = gam[c] * rsqrtf(var + 1e-5f);
  sc[c] = k; sh[c] = bet[c] - mean*k;
}

// zn -> h0 (bf16), h1 (bf16), c0 (f32), c1 (f32)
__global__ void bn_norm(const float* __restrict__ z, const float* __restrict__ sc, const float* __restrict__ sh,
                        u16* __restrict__ h0, u16* __restrict__ h1,
                        float* __restrict__ c0, float* __restrict__ c1){
  int bx = blockIdx.x; int rg = bx >> 2, cg = bx & 3;
  int c = cg*256 + threadIdx.x;
  float k = sc[c], b = sh[c];
  for (int r = rg*64; r < rg*64 + 64; ++r){
    float v = z[r*1024 + c]*k + b;
    u16 hv = f2bf(v);
    h0[r*1024 + c] = hv; h1[r*1024 + c] = hv;
    c0[r*1024 + c] = v;  c1[r*1024 + c] = v;
  }
}

// ---------------- weight convert (+gate-interleave permutation) --------------
__global__ void conv_w(const float* __restrict__ src, u16* __restrict__ dst,
                       int dstStride, int colOff, int permute){
  int c = blockIdx.x;
  int row = c;
  if (permute){ int gate = (c>>4)&3; int u = (c&15) | ((c>>6)<<4); row = (gate<<10) + u; }
  float4 v = ((const float4*)(src + (size_t)row*1024))[threadIdx.x];
  ushort4 o; o.x = f2bf(v.x); o.y = f2bf(v.y); o.z = f2bf(v.z); o.w = f2bf(v.w);
  ((ushort4*)(dst + (size_t)c*dstStride + colOff))[threadIdx.x] = o;
}

__global__ void bias_k(const float* __restrict__ bi0, const float* __restrict__ bh0,
                       const float* __restrict__ bi1, const float* __restrict__ bh1,
                       float* __restrict__ bx0, float* __restrict__ b1){
  int c = blockIdx.x*256 + threadIdx.x;           // 0..4095
  int gate = (c>>4)&3; int u = (c&15) | ((c>>6)<<4); int r = (gate<<10) + u;
  bx0[c] = bi0[r] + bh0[r];
  b1[c]  = bi1[r] + bh1[r];
}

// ---------------- GEMM core: C(128x128) = A(M,K) @ B(N,K)^T, bf16 MFMA ------
// A-operand: DIRECT global->VGPR (no LDS). A rows are L2-resident (h / zn /
// Feats-with-XCD-swizzle); each bf16x8 load = 16 rows x 64B fully-utilized
// L2 transactions. Register double-buffer (afA/afB), 1 K-step ahead.
// B-operand: global_load_lds, NBUF=4 x 8KB, 2 tiles in flight.
// Steady-state FIFO per iter: [stageB(k+2):2][loadA(k+1):4] -> vmcnt(6)
// retires B(k+1)+A(k): tile-k B landed one wait earlier, A(k) ready now.
// One s_barrier per K-step; stage(k+4) (buffer (k)&3) is issued after
// barrier(k+1), all waves consumed tile k by then -> race-free at NBUF=4.
// Tail: stage/loadA past nkt overfetch workspace-interior bytes (never used)
// to keep vmcnt constant -- no guards.
// LDS tile: row-major [128][32] u16 with 16B-slot swizzle (slot ^= (row>>1)&3)
// via pre-swizzled global source; read back with same XOR (2-way, free).
// MODE 0: store f32 gates+bias (x0 projection) to outf (ld 4096)
// MODE 1: LSTM layer-0 epilogue (add = x0proj matrix, incl. both biases)
// MODE 2: LSTM layer-1 epilogue (add = bias per col); also writes feats
// MODE 3: store f32 out + bias (ld 1024), unpermuted (linear head)
template<int MODE>
DEV void gemm_core(int bx, int by,
                   const u16* __restrict__ A0, const u16* __restrict__ A1, int KloA,
                   const u16* __restrict__ Bm, int K,
                   const float* __restrict__ add, float* __restrict__ cst,
                   u16* __restrict__ hout, u16* __restrict__ hout2,
                   float* __restrict__ outf,
                   u16* sB)                        // 4*4096 u16 (32 KB)
{
  const int t = threadIdx.x;
  const int lane = t & 63;
  const int w = t >> 6, wm = w >> 1, wn = w & 1;
  const int m0 = by*128, n0 = bx*128;

  f32x4 acc[4][4];
#pragma unroll
  for (int i = 0; i < 4; ++i)
#pragma unroll
    for (int j = 0; j < 4; ++j) acc[i][j] = (f32x4){0.f,0.f,0.f,0.f};

  const int rA = t >> 2;                         // B staging row (q=0); q=1 adds 64
  const int kswz = (((t & 3) ^ ((t >> 3) & 3)) << 3);
  const int nkt = K >> 5;

  auto stageB = [&](int kt, int b){
    const int k0 = kt << 5;
    u16* d = sB + b*4096;
#pragma unroll
    for (int q = 0; q < 2; ++q)
      async16(Bm + (size_t)(n0 + rA + q*64)*K + k0 + kswz, d + (t + q*256)*8);
  };

  // A-direct per-lane row pointers (lda = 1024 for all A matrices here)
  const int arow  = wm*64 + (lane & 15);
  const int akoff = (lane >> 4) * 8;
  const u16* pA0 = A0 + (size_t)(m0 + arow)*1024 + akoff;
  const u16* pA1 = ((MODE == 2) ? A1 : A0) + (size_t)(m0 + arow)*1024 + akoff;

  auto loadA = [&](bf16x8* af, int kt){
    const int k0 = kt << 5;
    const u16* p = (k0 < KloA) ? (pA0 + k0) : (pA1 + (k0 - KloA));
#pragma unroll
    for (int i = 0; i < 4; ++i) af[i] = *(const bf16x8*)(p + (size_t)i*16*1024);
  };

  // B read-side swizzle: f(row) = (lane>>1)&3 (i*16, wn*64 are 0 mod 8 rows)
  const int rdswz = (((lane >> 4) ^ ((lane >> 1) & 3)) << 3);

  bf16x8 afA[4], afB[4];
  stageB(0, 0); stageB(1, 1);
  loadA(afA, 0);

  for (int kt = 0; kt < nkt; kt += 2){
    // ---- even sub-iter: compute tile kt with afA -------------------------
    stageB(kt + 2, (kt + 2) & 3);
    loadA(afB, kt + 1);
    asm volatile("s_waitcnt vmcnt(6)" ::: "memory");
    __builtin_amdgcn_sched_barrier(0);
    __builtin_amdgcn_s_barrier();
    __builtin_amdgcn_sched_barrier(0);
    {
      const u16* pB = sB + (kt & 3)*4096;
      bf16x8 bfr[4];
#pragma unroll
      for (int i = 0; i < 4; ++i)
        bfr[i] = *(const bf16x8*)&pB[(wn*64 + i*16 + (lane & 15))*32 + rdswz];
      __builtin_amdgcn_s_setprio(1);
#pragma unroll
      for (int i = 0; i < 4; ++i)
#pragma unroll
        for (int j = 0; j < 4; ++j)
          acc[i][j] = __builtin_amdgcn_mfma_f32_16x16x32_bf16(afA[i], bfr[j], acc[i][j], 0, 0, 0);
      __builtin_amdgcn_s_setprio(0);
    }
    // ---- odd sub-iter: compute tile kt+1 with afB ------------------------
    stageB(kt + 3, (kt + 3) & 3);
    loadA(afA, kt + 2);
    asm volatile("s_waitcnt vmcnt(6)" ::: "memory");
    __builtin_amdgcn_sched_barrier(0);
    __builtin_amdgcn_s_barrier();
    __builtin_amdgcn_sched_barrier(0);
    {
      const u16* pB = sB + ((kt + 1) & 3)*4096;
      bf16x8 bfr[4];
#pragma unroll
      for (int i = 0; i < 4; ++i)
        bfr[i] = *(const bf16x8*)&pB[(wn*64 + i*16 + (lane & 15))*32 + rdswz];
      __builtin_amdgcn_s_setprio(1);
#pragma unroll
      for (int i = 0; i < 4; ++i)
#pragma unroll
        for (int j = 0; j < 4; ++j)
          acc[i][j] = __builtin_amdgcn_mfma_f32_16x16x32_bf16(afB[i], bfr[j], acc[i][j], 0, 0, 0);
      __builtin_amdgcn_s_setprio(0);
    }
  }

  const int s  = lane & 15;
  const int rq = (lane >> 4) * 4;

  if constexpr (MODE == 0 || MODE == 3){
    const int ldc = (MODE == 0) ? 4096 : 1024;
#pragma unroll
    for (int j = 0; j < 4; ++j){
      int col = n0 + wn*64 + j*16 + s;
      float bj = add[col];
#pragma unroll
      for (int i = 0; i < 4; ++i){
        int rowb = m0 + wm*64 + i*16 + rq;
#pragma unroll
        for (int r = 0; r < 4; ++r)
          outf[(size_t)(rowb + r)*ldc + col] = acc[i][j][r] + bj;
      }
    }
  } else {
    const int u = s + ((bx*2 + wn) << 4);     // hidden-unit index 0..1023
    int cidx[4]; float bj[4];
#pragma unroll
    for (int j = 0; j < 4; ++j){
      cidx[j] = n0 + wn*64 + j*16 + s;        // gate j lives at this col
      if (MODE == 2) bj[j] = add[cidx[j]];
    }
#pragma unroll
    for (int i = 0; i < 4; ++i){
      int rowb = m0 + wm*64 + i*16 + rq;
#pragma unroll
      for (int r = 0; r < 4; ++r){
        int row = rowb + r;
        float g0, g1, g2, g3;
        if (MODE == 1){
          const float* xp = add + (size_t)row*4096;
          g0 = acc[i][0][r] + xp[cidx[0]];
          g1 = acc[i][1][r] + xp[cidx[1]];
          g2 = acc[i][2][r] + xp[cidx[2]];
          g3 = acc[i][3][r] + xp[cidx[3]];
        } else {
          g0 = acc[i][0][r] + bj[0];
          g1 = acc[i][1][r] + bj[1];
          g2 = acc[i][2][r] + bj[2];
          g3 = acc[i][3][r] + bj[3];
        }
        float ig = sigf(g0), fg = sigf(g1), gg = tanh_(g2), og = sigf(g3);
        size_t si = (size_t)row*1024 + u;
        float cn = fg * cst[si] + ig * gg;
        cst[si] = cn;
        float hn = og * tanh_(cn);
        u16 hb = f2bf(hn);
        hout[si] = hb;
        if (MODE == 2) hout2[(size_t)row*32768 + u] = hb;  // feats[b][t][u]
      }
    }
  }
}

// ---- standalone GEMM (MODE 0 prep, MODE 3 head). SWZ: bijective XCD chunking
// so the 8 bx-blocks sharing one A-tile land on ONE XCD's L2 (grid (8,256)).
template<int MODE, int SWZ>
__global__ __launch_bounds__(256)
void gemm_k(const u16* __restrict__ A0, const u16* __restrict__ Bm, int K,
            const float* __restrict__ add, float* __restrict__ outf)
{
  __shared__ __align__(16) u16 sB[4*4096];
  int bx = blockIdx.x, by = blockIdx.y;
  if constexpr (SWZ){
    int lin = by * (int)gridDim.x + bx;   // hw: XCD = lin & 7
    int xcd = lin & 7, idx = lin >> 3;    // idx 0..255 within XCD
    by = xcd*32 + (idx >> 3);             // each XCD: 32 contiguous by-tiles
    bx = idx & 7;
  }
  gemm_core<MODE>(bx, by, A0, nullptr, 1<<20, Bm, K, add,
                  nullptr, nullptr, nullptr, outf, sB);
}

// ---- fused step: L1(t) (blocks by<8) runs concurrently with L0(t+1) (by>=8).
// roles: 0 = both (grid y=16), 1 = L0 only (y=8), 2 = L1 only (y=8).
__global__ __launch_bounds__(256)
void fused_step(const u16* __restrict__ h0in, const u16* __restrict__ h1in,
                const u16* __restrict__ Whh0p, const u16* __restrict__ W1p,
                const float* __restrict__ X0p, const float* __restrict__ B1,
                float* __restrict__ C0, float* __restrict__ C1,
                u16* __restrict__ h0out, u16* __restrict__ h1out,
                u16* __restrict__ feats, int roles)
{
  __shared__ __align__(16) u16 sB[4*4096];
  int by = blockIdx.y, isL0;
  if (roles == 0){ isL0 = (by >= 8); by &= 7; }
  else isL0 = (roles == 1);
  if (isL0)   // h0(next) = cell(X0p, h0in, C0)
    gemm_core<1>(blockIdx.x, by, h0in, nullptr, 1<<20, Whh0p, 1024, X0p,
                 C0, h0out, nullptr, nullptr, sB);
  else        // h1(next) = cell([h0in|h1in]@W1^T + B1, C1); writes feats
    gemm_core<2>(blockIdx.x, by, h0in, h1in, 1024, W1p, 2048, B1,
                 C1, h1out, feats, nullptr, sB);
}

// ---------------------------------------------------------------------------
extern "C" void kernel_launch(void* const* d_in, const int* in_sizes, int n_in,
                              void* d_out, int out_size, void* d_ws, size_t ws_size,
                              hipStream_t stream)
{
  (void)in_sizes; (void)n_in; (void)out_size; (void)ws_size;
  const float* z    = (const float*)d_in[0];
  const float* gam  = (const float*)d_in[1];
  const float* bet  = (const float*)d_in[2];
  const float* Wih0 = (const float*)d_in[3];
  const float* Whh0 = (const float*)d_in[4];
  const float* bih0 = (const float*)d_in[5];
  const float* bhh0 = (const float*)d_in[6];
  const float* Wih1 = (const float*)d_in[7];
  const float* Whh1 = (const float*)d_in[8];
  const float* bih1 = (const float*)d_in[9];
  const float* bhh1 = (const float*)d_in[10];
  const float* Wlin = (const float*)d_in[11];
  const float* blin = (const float*)d_in[12];
  float* out = (float*)d_out;

  char* p = (char*)d_ws;
  auto alloc = [&](size_t b) -> void* { void* r = (void*)p; p += (b + 255) & ~(size_t)255; return r; };
  u16*  Wih0p = (u16*)alloc((size_t)4096*1024*2);
  u16*  Whh0p = (u16*)alloc((size_t)4096*1024*2);
  u16*  W1p   = (u16*)alloc((size_t)4096*2048*2);   // [W_ih1 | W_hh1] along K
  u16*  Wlinp = (u16*)alloc((size_t)1024*1024*2);
  float* Bx0  = (float*)alloc(4096*4);
  float* B1   = (float*)alloc(4096*4);
  float* X0p  = (float*)alloc((size_t)1024*4096*4);
  u16*  H0a   = (u16*)alloc((size_t)1024*1024*2);
  u16*  H0b   = (u16*)alloc((size_t)1024*1024*2);
  u16*  H1a   = (u16*)alloc((size_t)1024*1024*2);
  u16*  H1b   = (u16*)alloc((size_t)1024*1024*2);
  float* C0   = (float*)alloc((size_t)1024*1024*4);
  float* C1   = (float*)alloc((size_t)1024*1024*4);
  u16*  Feats = (u16*)alloc((size_t)1024*32*1024*2);
  float* PS   = (float*)alloc(16*1024*4);
  float* PQ   = (float*)alloc(16*1024*4);
  float* Sc   = (float*)alloc(1024*4);
  float* Sh   = (float*)alloc(1024*4);

  // prep
  bn_stats<<<64, 256, 0, stream>>>(z, PS, PQ);
  bn_fin<<<4, 256, 0, stream>>>(PS, PQ, gam, bet, Sc, Sh);
  bn_norm<<<64, 256, 0, stream>>>(z, Sc, Sh, H0a, H1a, C0, C1);
  conv_w<<<4096, 256, 0, stream>>>(Wih0, Wih0p, 1024, 0, 1);
  conv_w<<<4096, 256, 0, stream>>>(Whh0, Whh0p, 1024, 0, 1);
  conv_w<<<4096, 256, 0, stream>>>(Wih1, W1p, 2048, 0, 1);
  conv_w<<<4096, 256, 0, stream>>>(Whh1, W1p, 2048, 1024, 1);
  conv_w<<<1024, 256, 0, stream>>>(Wlin, Wlinp, 1024, 0, 0);
  bias_k<<<16, 256, 0, stream>>>(bih0, bhh0, bih1, bhh1, Bx0, B1);

  // x0_proj = zn @ W_ih0p^T + (b_ih0 + b_hh0)   (constant over steps)
  gemm_k<0,0><<<dim3(32,8), 256, 0, stream>>>(H0a, Wih0p, 1024, Bx0, X0p);

  u16* h0b[2] = {H0a, H0b};
  u16* h1b[2] = {H1a, H1b};

  // h0(1) <- h0(0): L0 alone (nothing to overlap with yet)
  fused_step<<<dim3(32,8), 256, 0, stream>>>(h0b[0], nullptr, Whh0p, W1p, X0p, B1,
                                             C0, C1, h0b[1], nullptr, nullptr, 1);
  // steps t=0..30: L1(t) uses h0(t+1); concurrently L0 computes h0(t+2)
  for (int t = 0; t < 31; ++t){
    fused_step<<<dim3(32,16), 256, 0, stream>>>(
        h0b[(t+1)&1], h1b[t&1], Whh0p, W1p, X0p, B1,
        C0, C1, h0b[t&1], h1b[(t+1)&1], Feats + (size_t)t*1024, 0);
  }
  // final L1(31): uses h0(32)=h0b[0], h1 state h1b[1]
  fused_step<<<dim3(32,8), 256, 0, stream>>>(h0b[0], h1b[1], Whh0p, W1p, X0p, B1,
                                             C0, C1, nullptr, h1b[0], Feats + (size_t)31*1024, 2);

  // out = feats @ W_lin^T + b_lin  (XCD-chunked swizzle for A-tile L2 reuse)
  gemm_k<3,1><<<dim3(8,256), 256, 0, stream>>>(Feats, Wlinp, 1024, blin, out);
}

// Round 4
// 1745.234 us; speedup vs baseline: 1.3721x; 1.3721x over previous
//
#include <hip/hip_runtime.h>

#define DEV __device__ __forceinline__

typedef unsigned short u16;
using bf16x8 = __attribute__((ext_vector_type(8))) __bf16;
using f32x4  = __attribute__((ext_vector_type(4))) float;

DEV u16 f2bf(float f){
  unsigned u = __float_as_uint(f);
  u += 0x7fffu + ((u >> 16) & 1u);   // round-to-nearest-even
  return (u16)(u >> 16);
}
DEV float sigf(float x){ return 1.f / (1.f + __expf(-x)); }
DEV float tanh_(float x){ return 2.f / (1.f + __expf(-2.f*x)) - 1.f; } // safe at +/-inf

DEV void async16(const u16* g, u16* l){
  __builtin_amdgcn_global_load_lds(
      (const __attribute__((address_space(1))) unsigned int*)g,
      (__attribute__((address_space(3))) unsigned int*)l, 16, 0, 0);
}

// ---------------- BatchNorm (training-mode batch stats, biased var) ----------
__global__ void bn_stats(const float* __restrict__ z, float* __restrict__ ps, float* __restrict__ pq){
  int bx = blockIdx.x; int rg = bx >> 2, cg = bx & 3;
  int c = cg*256 + threadIdx.x;
  float s = 0.f, q = 0.f;
  for (int r = rg*64; r < rg*64 + 64; ++r){ float v = z[r*1024 + c]; s += v; q += v*v; }
  ps[rg*1024 + c] = s; pq[rg*1024 + c] = q;
}

__global__ void bn_fin(const float* __restrict__ ps, const float* __restrict__ pq,
                       const float* __restrict__ gam, const float* __restrict__ bet,
                       float* __restrict__ sc, float* __restrict__ sh){
  int c = blockIdx.x*256 + threadIdx.x;
  float s = 0.f, q = 0.f;
  for (int rg = 0; rg < 16; ++rg){ s += ps[rg*1024 + c]; q += pq[rg*1024 + c]; }
  float mean = s * (1.f/1024.f);
  float var  = q * (1.f/1024.f) - mean*mean;
  float k = gam[c] * rsqrtf(var + 1e-5f);
  sc[c] = k; sh[c] = bet[c] - mean*k;
}

// zn -> h0 (bf16), h1 (bf16), c0 (f32), c1 (f32)
__global__ void bn_norm(const float* __restrict__ z, const float* __restrict__ sc, const float* __restrict__ sh,
                        u16* __restrict__ h0, u16* __restrict__ h1,
                        float* __restrict__ c0, float* __restrict__ c1){
  int bx = blockIdx.x; int rg = bx >> 2, cg = bx & 3;
  int c = cg*256 + threadIdx.x;
  float k = sc[c], b = sh[c];
  for (int r = rg*64; r < rg*64 + 64; ++r){
    float v = z[r*1024 + c]*k + b;
    u16 hv = f2bf(v);
    h0[r*1024 + c] = hv; h1[r*1024 + c] = hv;
    c0[r*1024 + c] = v;  c1[r*1024 + c] = v;
  }
}

// ---------------- weight convert (+gate-interleave permutation) --------------
__global__ void conv_w(const float* __restrict__ src, u16* __restrict__ dst,
                       int dstStride, int colOff, int permute){
  int c = blockIdx.x;
  int row = c;
  if (permute){ int gate = (c>>4)&3; int u = (c&15) | ((c>>6)<<4); row = (gate<<10) + u; }
  float4 v = ((const float4*)(src + (size_t)row*1024))[threadIdx.x];
  ushort4 o; o.x = f2bf(v.x); o.y = f2bf(v.y); o.z = f2bf(v.z); o.w = f2bf(v.w);
  ((ushort4*)(dst + (size_t)c*dstStride + colOff))[threadIdx.x] = o;
}

__global__ void bias_k(const float* __restrict__ bi0, const float* __restrict__ bh0,
                       const float* __restrict__ bi1, const float* __restrict__ bh1,
                       float* __restrict__ bx0, float* __restrict__ b1){
  int c = blockIdx.x*256 + threadIdx.x;           // 0..4095
  int gate = (c>>4)&3; int u = (c&15) | ((c>>6)<<4); int r = (gate<<10) + u;
  bx0[c] = bi0[r] + bh0[r];
  b1[c]  = bi1[r] + bh1[r];
}

// ---------------- GEMM core: C(128x128) = A(M,K) @ B(N,K)^T, bf16 MFMA ------
// BK=64, NBUF=2 (A 16KB + B 16KB per buf, 64KB total -> 2 blocks/CU).
// Minimum-2-phase schedule (T3): per iter {stage(next) FIRST; ds_read cur;
// MFMA; vmcnt(0)+barrier}. Stage flight is hidden under one full compute
// phase; exactly ONE barrier per 64-K (half the old cadence).
// Race-free: stage(k+1) writes buf^1, whose iter-(k-1) reads completed
// before the trailing barrier of iter k-1 (lgkm waits before MFMA).
// LDS tile: row-major [128][64] u16 (8 x 16B slots/row), slot swizzle
//   slot_eff = slot ^ (row&7), applied via pre-swizzled GLOBAL source
// (global_load_lds dest stays linear) and the same XOR on ds_read ->
// <=2-way conflicts (free, m136).
// MODE 0: store f32 gates+bias (x0 projection) to outf (ld 4096)
// MODE 1: LSTM layer-0 epilogue (add = x0proj matrix, incl. both biases)
// MODE 2: LSTM layer-1 epilogue (add = bias per col); also writes feats
// MODE 3: store f32 out + bias (ld 1024), unpermuted (linear head)
template<int MODE>
DEV void gemm_core(int bx, int by,
                   const u16* __restrict__ A0, const u16* __restrict__ A1, int KloA,
                   const u16* __restrict__ Bm, int K,
                   const float* __restrict__ add, float* __restrict__ cst,
                   u16* __restrict__ hout, u16* __restrict__ hout2,
                   float* __restrict__ outf,
                   u16* sA, u16* sB)                 // each 2*8192 u16 (32 KB)
{
  const int t = threadIdx.x;
  const int lane = t & 63;
  const int w = t >> 6, wm = w >> 1, wn = w & 1;
  const int m0 = by*128, n0 = bx*128;

  f32x4 acc[4][4];
#pragma unroll
  for (int i = 0; i < 4; ++i)
#pragma unroll
    for (int j = 0; j < 4; ++j) acc[i][j] = (f32x4){0.f,0.f,0.f,0.f};

  // staging: round p covers rows p*32..p*32+31; thread t -> row p*32+(t>>3),
  // 16B slot (t&7). Source slot pre-swizzled: (t&7) ^ (row&7) = (t&7)^((t>>3)&7).
  const int srow = t >> 3;                      // 0..31 within round
  const int kswz = (((t & 7) ^ ((t >> 3) & 7)) << 3);   // elems
  const int nkt = K >> 6;

  auto stageM = [&](const u16* P, int ld, int r0, int k0, u16* dst){
#pragma unroll
    for (int p = 0; p < 4; ++p)
      async16(P + (size_t)(r0 + p*32 + srow)*ld + k0 + kswz,
              dst + p*2048 + t*8);
  };
  auto stage = [&](int kt, int b){
    const int k0 = kt << 6;
    const u16* aPart; int kk;
    if (k0 < KloA){ aPart = A0; kk = k0; } else { aPart = A1; kk = k0 - KloA; }
    stageM(aPart, 1024, m0, kk, sA + b*8192);
    stageM(Bm,    K,    n0, k0, sB + b*8192);
  };

  // read-side: row = (base%8==0) + (lane&15) -> row&7 = lane&7
  const int rsel = lane >> 4;                   // 16B sub-slot within 32-K
  const int rxor = lane & 7;

  stage(0, 0);
  asm volatile("s_waitcnt vmcnt(0)" ::: "memory");
  __builtin_amdgcn_sched_barrier(0);
  __builtin_amdgcn_s_barrier();
  __builtin_amdgcn_sched_barrier(0);

  for (int kt = 0; kt < nkt; ++kt){
    if (kt + 1 < nkt) stage(kt + 1, (kt + 1) & 1);   // issue-early (T14 order)
    const u16* pA = sA + (kt & 1)*8192;
    const u16* pB = sB + (kt & 1)*8192;
#pragma unroll
    for (int ksub = 0; ksub < 2; ++ksub){
      bf16x8 af[4], bfr[4];
#pragma unroll
      for (int i = 0; i < 4; ++i){
        int ra = wm*64 + i*16 + (lane & 15);
        int rb = wn*64 + i*16 + (lane & 15);
        int sl = ((ksub*4 + rsel) ^ rxor) << 3;
        af[i]  = *(const bf16x8*)&pA[ra*64 + sl];
        bfr[i] = *(const bf16x8*)&pB[rb*64 + sl];
      }
      __builtin_amdgcn_s_setprio(1);
#pragma unroll
      for (int i = 0; i < 4; ++i)
#pragma unroll
        for (int j = 0; j < 4; ++j)
          acc[i][j] = __builtin_amdgcn_mfma_f32_16x16x32_bf16(af[i], bfr[j], acc[i][j], 0, 0, 0);
      __builtin_amdgcn_s_setprio(0);
    }
    if (kt + 1 < nkt){
      asm volatile("s_waitcnt vmcnt(0)" ::: "memory");   // next tile landed
      __builtin_amdgcn_sched_barrier(0);
      __builtin_amdgcn_s_barrier();
      __builtin_amdgcn_sched_barrier(0);
    }
  }

  const int s  = lane & 15;
  const int rq = (lane >> 4) * 4;

  if constexpr (MODE == 0 || MODE == 3){
    const int ldc = (MODE == 0) ? 4096 : 1024;
#pragma unroll
    for (int j = 0; j < 4; ++j){
      int col = n0 + wn*64 + j*16 + s;
      float bj = add[col];
#pragma unroll
      for (int i = 0; i < 4; ++i){
        int rowb = m0 + wm*64 + i*16 + rq;
#pragma unroll
        for (int r = 0; r < 4; ++r)
          outf[(size_t)(rowb + r)*ldc + col] = acc[i][j][r] + bj;
      }
    }
  } else {
    const int u = s + ((bx*2 + wn) << 4);     // hidden-unit index 0..1023
    int cidx[4]; float bj[4];
#pragma unroll
    for (int j = 0; j < 4; ++j){
      cidx[j] = n0 + wn*64 + j*16 + s;        // gate j lives at this col
      if (MODE == 2) bj[j] = add[cidx[j]];
    }
#pragma unroll
    for (int i = 0; i < 4; ++i){
      int rowb = m0 + wm*64 + i*16 + rq;
#pragma unroll
      for (int r = 0; r < 4; ++r){
        int row = rowb + r;
        float g0, g1, g2, g3;
        if (MODE == 1){
          const float* xp = add + (size_t)row*4096;
          g0 = acc[i][0][r] + xp[cidx[0]];
          g1 = acc[i][1][r] + xp[cidx[1]];
          g2 = acc[i][2][r] + xp[cidx[2]];
          g3 = acc[i][3][r] + xp[cidx[3]];
        } else {
          g0 = acc[i][0][r] + bj[0];
          g1 = acc[i][1][r] + bj[1];
          g2 = acc[i][2][r] + bj[2];
          g3 = acc[i][3][r] + bj[3];
        }
        float ig = sigf(g0), fg = sigf(g1), gg = tanh_(g2), og = sigf(g3);
        size_t si = (size_t)row*1024 + u;
        float cn = fg * cst[si] + ig * gg;
        cst[si] = cn;
        float hn = og * tanh_(cn);
        u16 hb = f2bf(hn);
        hout[si] = hb;
        if (MODE == 2) hout2[(size_t)row*32768 + u] = hb;  // feats[b][t][u]
      }
    }
  }
}

// ---- standalone GEMM (MODE 0 prep, MODE 3 head). SWZ: bijective XCD chunking
// so the 8 bx-blocks sharing one A-tile land on ONE XCD's L2 (grid (8,256)).
template<int MODE, int SWZ>
__global__ __launch_bounds__(256)
void gemm_k(const u16* __restrict__ A0, const u16* __restrict__ Bm, int K,
            const float* __restrict__ add, float* __restrict__ outf)
{
  __shared__ __align__(16) u16 sA[2*8192];
  __shared__ __align__(16) u16 sB[2*8192];
  int bx = blockIdx.x, by = blockIdx.y;
  if constexpr (SWZ){
    int lin = by * (int)gridDim.x + bx;   // hw: XCD = lin & 7
    int xcd = lin & 7, idx = lin >> 3;    // idx 0..255 within XCD
    by = xcd*32 + (idx >> 3);             // each XCD: 32 contiguous by-tiles
    bx = idx & 7;
  }
  gemm_core<MODE>(bx, by, A0, nullptr, 1<<20, Bm, K, add,
                  nullptr, nullptr, nullptr, outf, sA, sB);
}

// ---- fused step: L1(t) (blocks by<8) runs concurrently with L0(t+1) (by>=8).
// roles: 0 = both (grid y=16), 1 = L0 only (y=8), 2 = L1 only (y=8).
__global__ __launch_bounds__(256)
void fused_step(const u16* __restrict__ h0in, const u16* __restrict__ h1in,
                const u16* __restrict__ Whh0p, const u16* __restrict__ W1p,
                const float* __restrict__ X0p, const float* __restrict__ B1,
                float* __restrict__ C0, float* __restrict__ C1,
                u16* __restrict__ h0out, u16* __restrict__ h1out,
                u16* __restrict__ feats, int roles)
{
  __shared__ __align__(16) u16 sA[2*8192];
  __shared__ __align__(16) u16 sB[2*8192];
  int by = blockIdx.y, isL0;
  if (roles == 0){ isL0 = (by >= 8); by &= 7; }
  else isL0 = (roles == 1);
  if (isL0)   // h0(next) = cell(X0p, h0in, C0)
    gemm_core<1>(blockIdx.x, by, h0in, nullptr, 1<<20, Whh0p, 1024, X0p,
                 C0, h0out, nullptr, nullptr, sA, sB);
  else        // h1(next) = cell([h0in|h1in]@W1^T + B1, C1); writes feats
    gemm_core<2>(blockIdx.x, by, h0in, h1in, 1024, W1p, 2048, B1,
                 C1, h1out, feats, nullptr, sA, sB);
}

// ---------------------------------------------------------------------------
extern "C" void kernel_launch(void* const* d_in, const int* in_sizes, int n_in,
                              void* d_out, int out_size, void* d_ws, size_t ws_size,
                              hipStream_t stream)
{
  (void)in_sizes; (void)n_in; (void)out_size; (void)ws_size;
  const float* z    = (const float*)d_in[0];
  const float* gam  = (const float*)d_in[1];
  const float* bet  = (const float*)d_in[2];
  const float* Wih0 = (const float*)d_in[3];
  const float* Whh0 = (const float*)d_in[4];
  const float* bih0 = (const float*)d_in[5];
  const float* bhh0 = (const float*)d_in[6];
  const float* Wih1 = (const float*)d_in[7];
  const float* Whh1 = (const float*)d_in[8];
  const float* bih1 = (const float*)d_in[9];
  const float* bhh1 = (const float*)d_in[10];
  const float* Wlin = (const float*)d_in[11];
  const float* blin = (const float*)d_in[12];
  float* out = (float*)d_out;

  char* p = (char*)d_ws;
  auto alloc = [&](size_t b) -> void* { void* r = (void*)p; p += (b + 255) & ~(size_t)255; return r; };
  u16*  Wih0p = (u16*)alloc((size_t)4096*1024*2);
  u16*  Whh0p = (u16*)alloc((size_t)4096*1024*2);
  u16*  W1p   = (u16*)alloc((size_t)4096*2048*2);   // [W_ih1 | W_hh1] along K
  u16*  Wlinp = (u16*)alloc((size_t)1024*1024*2);
  float* Bx0  = (float*)alloc(4096*4);
  float* B1   = (float*)alloc(4096*4);
  float* X0p  = (float*)alloc((size_t)1024*4096*4);
  u16*  H0a   = (u16*)alloc((size_t)1024*1024*2);
  u16*  H0b   = (u16*)alloc((size_t)1024*1024*2);
  u16*  H1a   = (u16*)alloc((size_t)1024*1024*2);
  u16*  H1b   = (u16*)alloc((size_t)1024*1024*2);
  float* C0   = (float*)alloc((size_t)1024*1024*4);
  float* C1   = (float*)alloc((size_t)1024*1024*4);
  u16*  Feats = (u16*)alloc((size_t)1024*32*1024*2);
  float* PS   = (float*)alloc(16*1024*4);
  float* PQ   = (float*)alloc(16*1024*4);
  float* Sc   = (float*)alloc(1024*4);
  float* Sh   = (float*)alloc(1024*4);

  // prep
  bn_stats<<<64, 256, 0, stream>>>(z, PS, PQ);
  bn_fin<<<4, 256, 0, stream>>>(PS, PQ, gam, bet, Sc, Sh);
  bn_norm<<<64, 256, 0, stream>>>(z, Sc, Sh, H0a, H1a, C0, C1);
  conv_w<<<4096, 256, 0, stream>>>(Wih0, Wih0p, 1024, 0, 1);
  conv_w<<<4096, 256, 0, stream>>>(Whh0, Whh0p, 1024, 0, 1);
  conv_w<<<4096, 256, 0, stream>>>(Wih1, W1p, 2048, 0, 1);
  conv_w<<<4096, 256, 0, stream>>>(Whh1, W1p, 2048, 1024, 1);
  conv_w<<<1024, 256, 0, stream>>>(Wlin, Wlinp, 1024, 0, 0);
  bias_k<<<16, 256, 0, stream>>>(bih0, bhh0, bih1, bhh1, Bx0, B1);

  // x0_proj = zn @ W_ih0p^T + (b_ih0 + b_hh0)   (constant over steps)
  gemm_k<0,0><<<dim3(32,8), 256, 0, stream>>>(H0a, Wih0p, 1024, Bx0, X0p);

  u16* h0b[2] = {H0a, H0b};
  u16* h1b[2] = {H1a, H1b};

  // h0(1) <- h0(0): L0 alone (nothing to overlap with yet)
  fused_step<<<dim3(32,8), 256, 0, stream>>>(h0b[0], nullptr, Whh0p, W1p, X0p, B1,
                                             C0, C1, h0b[1], nullptr, nullptr, 1);
  // steps t=0..30: L1(t) uses h0(t+1); concurrently L0 computes h0(t+2)
  for (int t = 0; t < 31; ++t){
    fused_step<<<dim3(32,16), 256, 0, stream>>>(
        h0b[(t+1)&1], h1b[t&1], Whh0p, W1p, X0p, B1,
        C0, C1, h0b[t&1], h1b[(t+1)&1], Feats + (size_t)t*1024, 0);
  }
  // final L1(31): uses h0(32)=h0b[0], h1 state h1b[1]
  fused_step<<<dim3(32,8), 256, 0, stream>>>(h0b[0], h1b[1], Whh0p, W1p, X0p, B1,
                                             C0, C1, nullptr, h1b[0], Feats + (size_t)31*1024, 2);

  // out = feats @ W_lin^T + b_lin  (XCD-chunked swizzle for A-tile L2 reuse)
  gemm_k<3,1><<<dim3(8,256), 256, 0, stream>>>(Feats, Wlinp, 1024, blin, out);
}

// Round 5
// 1482.087 us; speedup vs baseline: 1.6158x; 1.1776x over previous
//
#include <hip/hip_runtime.h>

#define DEV __device__ __forceinline__

typedef unsigned short u16;
using bf16x8 = __attribute__((ext_vector_type(8))) __bf16;
using f32x4  = __attribute__((ext_vector_type(4))) float;

DEV u16 f2bf(float f){
  unsigned u = __float_as_uint(f);
  u += 0x7fffu + ((u >> 16) & 1u);   // round-to-nearest-even
  return (u16)(u >> 16);
}
DEV float sigf(float x){ return 1.f / (1.f + __expf(-x)); }
DEV float tanh_(float x){ return 2.f / (1.f + __expf(-2.f*x)) - 1.f; } // safe at +/-inf

DEV void async16(const u16* g, u16* l){
  __builtin_amdgcn_global_load_lds(
      (const __attribute__((address_space(1))) unsigned int*)g,
      (__attribute__((address_space(3))) unsigned int*)l, 16, 0, 0);
}

// ---------------- BatchNorm (training-mode batch stats, biased var) ----------
__global__ void bn_stats(const float* __restrict__ z, float* __restrict__ ps, float* __restrict__ pq){
  int bx = blockIdx.x; int rg = bx >> 2, cg = bx & 3;
  int c = cg*256 + threadIdx.x;
  float s = 0.f, q = 0.f;
  for (int r = rg*64; r < rg*64 + 64; ++r){ float v = z[r*1024 + c]; s += v; q += v*v; }
  ps[rg*1024 + c] = s; pq[rg*1024 + c] = q;
}

__global__ void bn_fin(const float* __restrict__ ps, const float* __restrict__ pq,
                       const float* __restrict__ gam, const float* __restrict__ bet,
                       float* __restrict__ sc, float* __restrict__ sh){
  int c = blockIdx.x*256 + threadIdx.x;
  float s = 0.f, q = 0.f;
  for (int rg = 0; rg < 16; ++rg){ s += ps[rg*1024 + c]; q += pq[rg*1024 + c]; }
  float mean = s * (1.f/1024.f);
  float var  = q * (1.f/1024.f) - mean*mean;
  float k = gam[c] * rsqrtf(var + 1e-5f);
  sc[c] = k; sh[c] = bet[c] - mean*k;
}

// zn -> h0 (bf16), h1 (bf16), c0 (f32), c1 (f32)
__global__ void bn_norm(const float* __restrict__ z, const float* __restrict__ sc, const float* __restrict__ sh,
                        u16* __restrict__ h0, u16* __restrict__ h1,
                        float* __restrict__ c0, float* __restrict__ c1){
  int bx = blockIdx.x; int rg = bx >> 2, cg = bx & 3;
  int c = cg*256 + threadIdx.x;
  float k = sc[c], b = sh[c];
  for (int r = rg*64; r < rg*64 + 64; ++r){
    float v = z[r*1024 + c]*k + b;
    u16 hv = f2bf(v);
    h0[r*1024 + c] = hv; h1[r*1024 + c] = hv;
    c0[r*1024 + c] = v;  c1[r*1024 + c] = v;
  }
}

// ---------------- weight pack: MFMA-fragment order (+gate permutation) -------
// Chunk c = ((((bx*nkt + kt)*2 + ksub)*2 + wn)*4 + j): 1KB = 64 lanes x 16B.
// Lane l holds B[n = bx*128 + wn*64 + j*16 + (l&15)][k = kt*64+ksub*32+(l>>4)*8 ..+8].
// permute: packed N-index -> source row (gate-interleave), sources ld=1024.
__global__ void pack_w(const float* __restrict__ src0, const float* __restrict__ src1,
                       int KloA, int K, int permute, u16* __restrict__ dst){
  int c = blockIdx.x*4 + (threadIdx.x >> 6);
  int lane = threadIdx.x & 63;
  int j = c & 3, wn = (c>>2)&1, ksub = (c>>3)&1;
  int rest = c >> 4;
  int nkt = K >> 6;
  int kt = rest % nkt, bx = rest / nkt;
  int rn = bx*128 + wn*64 + j*16 + (lane & 15);
  int row = rn;
  if (permute){ int gate=(rn>>4)&3; int u=(rn&15)|((rn>>6)<<4); row=(gate<<10)+u; }
  int k0 = kt*64 + ksub*32 + (lane>>4)*8;
  const float* s; int kk;
  if (k0 < KloA){ s = src0; kk = k0; } else { s = src1; kk = k0 - KloA; }
  const float4* v = (const float4*)(s + (size_t)row*1024 + kk);
  float4 a = v[0], b = v[1];
  ushort4 o0; o0.x=f2bf(a.x); o0.y=f2bf(a.y); o0.z=f2bf(a.z); o0.w=f2bf(a.w);
  ushort4 o1; o1.x=f2bf(b.x); o1.y=f2bf(b.y); o1.z=f2bf(b.z); o1.w=f2bf(b.w);
  ushort4* d = (ushort4*)(dst + ((size_t)c<<9) + lane*8);
  d[0]=o0; d[1]=o1;
}

__global__ void bias_k(const float* __restrict__ bi0, const float* __restrict__ bh0,
                       const float* __restrict__ bi1, const float* __restrict__ bh1,
                       float* __restrict__ bx0, float* __restrict__ b1){
  int c = blockIdx.x*256 + threadIdx.x;           // 0..4095
  int gate = (c>>4)&3; int u = (c&15) | ((c>>6)<<4); int r = (gate<<10) + u;
  bx0[c] = bi0[r] + bh0[r];
  b1[c]  = bi1[r] + bh1[r];
}

// ---------------- GEMM core: C(128x128) = A(M,K) @ B(N,K)^T, bf16 MFMA ------
// A: global_load_lds -> LDS, BK=64, NBUF=3 (48KB), single barrier per iter,
//    16B-slot XOR swizzle (slot ^= row&7) via pre-swizzled global source.
// B: fragment-PACKED global layout, loaded DIRECT global->VGPR as coalesced
//    1KB wave-loads; ksub-granular register double-buffer bP/bQ; no LDS, no
//    barrier dependence -- prefetch rides across barriers.
// vmcnt: per iter issues B(k,1):4, B(k+1,0):4, A(k+2):4 (clamped tail keeps
// counts exact). Compiler retires bP/bQ before their MFMAs. End-of-iter
// vmcnt(8) retires A(k+1), leaving {B(k+1,0), A(k+2)} in flight.
// Race-free at NBUF=3: stage(k+2) targets buf (k-1)%3, last read iter k-1,
// separated by the end-of-(k-1) barrier.
// MODE 0: store f32 gates+bias (x0 projection) to outf (ld 4096)
// MODE 1: LSTM layer-0 epilogue (add = x0proj matrix, incl. both biases)
// MODE 2: LSTM layer-1 epilogue (add = bias per col); also writes feats
// MODE 3: store f32 out + bias (ld 1024), unpermuted (linear head)
template<int MODE>
DEV void gemm_core(int bx, int by,
                   const u16* __restrict__ A0, const u16* __restrict__ A1, int KloA,
                   const u16* __restrict__ Bp, int K,
                   const float* __restrict__ add, float* __restrict__ cst,
                   u16* __restrict__ hout, u16* __restrict__ hout2,
                   float* __restrict__ outf,
                   u16* sA)                          // 3*8192 u16 (48 KB)
{
  const int t = threadIdx.x;
  const int lane = t & 63;
  const int w = t >> 6, wm = w >> 1, wn = w & 1;
  const int m0 = by*128, n0 = bx*128;

  f32x4 acc[4][4];
#pragma unroll
  for (int i = 0; i < 4; ++i)
#pragma unroll
    for (int j = 0; j < 4; ++j) acc[i][j] = (f32x4){0.f,0.f,0.f,0.f};

  const int srow = t >> 3;                      // staging row within 32-row round
  const int kswz = (((t & 7) ^ ((t >> 3) & 7)) << 3);   // pre-swizzled src slot
  const int nkt = K >> 6;

  auto stageA = [&](int kt, int b){
    const int k0 = kt << 6;
    const u16* aPart; int kk;
    if (k0 < KloA){ aPart = A0; kk = k0; } else { aPart = A1; kk = k0 - KloA; }
    u16* dst = sA + b*8192;
#pragma unroll
    for (int p = 0; p < 4; ++p)
      async16(aPart + (size_t)(m0 + p*32 + srow)*1024 + kk + kswz,
              dst + p*2048 + t*8);
  };

  // packed-B wave pointer: 4 j-chunks contiguous (4KB) per (kt,ksub,wn)
  const u16* BpL = Bp + lane*8;
  auto loadB = [&](bf16x8* b, int kt, int ksub){
    const u16* p = BpL + (((((size_t)bx*nkt + kt)*2 + ksub)*2 + wn) << 11);
#pragma unroll
    for (int j = 0; j < 4; ++j) b[j] = *(const bf16x8*)(p + (size_t)j*512);
  };

  // A read-side swizzle params (row&7 == lane&7 for all frag rows)
  const int rsel = lane >> 4;
  const int rxor = lane & 7;

  bf16x8 bP[4], bQ[4];
  stageA(0, 0); stageA(1, 1);
  loadB(bP, 0, 0);
  asm volatile("s_waitcnt vmcnt(0)" ::: "memory");
  __builtin_amdgcn_sched_barrier(0);
  __builtin_amdgcn_s_barrier();
  __builtin_amdgcn_sched_barrier(0);

  for (int kt = 0; kt < nkt; ++kt){
    const u16* pA = sA + (kt % 3)*8192;
    // ---- ksub 0: compute with bP; prefetch bQ = B(kt,1) --------------------
    loadB(bQ, kt, 1);
    {
      bf16x8 af[4];
#pragma unroll
      for (int i = 0; i < 4; ++i){
        int ra = wm*64 + i*16 + (lane & 15);
        int sl = ((0*4 + rsel) ^ rxor) << 3;
        af[i] = *(const bf16x8*)&pA[ra*64 + sl];
      }
      __builtin_amdgcn_s_setprio(1);
#pragma unroll
      for (int i = 0; i < 4; ++i)
#pragma unroll
        for (int j = 0; j < 4; ++j)
          acc[i][j] = __builtin_amdgcn_mfma_f32_16x16x32_bf16(af[i], bP[j], acc[i][j], 0, 0, 0);
      __builtin_amdgcn_s_setprio(0);
    }
    // ---- ksub 1: compute with bQ; prefetch bP = B(kt+1,0); stage A(kt+2) ---
    {
      int ktn = (kt + 1 < nkt) ? kt + 1 : nkt - 1;        // clamp: exact counts
      int kts = (kt + 2 < nkt) ? kt + 2 : nkt - 1;
      loadB(bP, ktn, 0);
      stageA(kts, (kt + 2) % 3);
      bf16x8 af[4];
#pragma unroll
      for (int i = 0; i < 4; ++i){
        int ra = wm*64 + i*16 + (lane & 15);
        int sl = ((1*4 + rsel) ^ rxor) << 3;
        af[i] = *(const bf16x8*)&pA[ra*64 + sl];
      }
      __builtin_amdgcn_s_setprio(1);
#pragma unroll
      for (int i = 0; i < 4; ++i)
#pragma unroll
        for (int j = 0; j < 4; ++j)
          acc[i][j] = __builtin_amdgcn_mfma_f32_16x16x32_bf16(af[i], bQ[j], acc[i][j], 0, 0, 0);
      __builtin_amdgcn_s_setprio(0);
    }
    asm volatile("s_waitcnt vmcnt(8)" ::: "memory");      // A(kt+1) landed
    __builtin_amdgcn_sched_barrier(0);
    __builtin_amdgcn_s_barrier();
    __builtin_amdgcn_sched_barrier(0);
  }

  const int s  = lane & 15;
  const int rq = (lane >> 4) * 4;

  if constexpr (MODE == 0 || MODE == 3){
    const int ldc = (MODE == 0) ? 4096 : 1024;
#pragma unroll
    for (int j = 0; j < 4; ++j){
      int col = n0 + wn*64 + j*16 + s;
      float bj = add[col];
#pragma unroll
      for (int i = 0; i < 4; ++i){
        int rowb = m0 + wm*64 + i*16 + rq;
#pragma unroll
        for (int r = 0; r < 4; ++r)
          outf[(size_t)(rowb + r)*ldc + col] = acc[i][j][r] + bj;
      }
    }
  } else {
    const int u = s + ((bx*2 + wn) << 4);     // hidden-unit index 0..1023
    int cidx[4]; float bj[4];
#pragma unroll
    for (int j = 0; j < 4; ++j){
      cidx[j] = n0 + wn*64 + j*16 + s;        // gate j lives at this col
      if (MODE == 2) bj[j] = add[cidx[j]];
    }
#pragma unroll
    for (int i = 0; i < 4; ++i){
      int rowb = m0 + wm*64 + i*16 + rq;
#pragma unroll
      for (int r = 0; r < 4; ++r){
        int row = rowb + r;
        float g0, g1, g2, g3;
        if (MODE == 1){
          const float* xp = add + (size_t)row*4096;
          g0 = acc[i][0][r] + xp[cidx[0]];
          g1 = acc[i][1][r] + xp[cidx[1]];
          g2 = acc[i][2][r] + xp[cidx[2]];
          g3 = acc[i][3][r] + xp[cidx[3]];
        } else {
          g0 = acc[i][0][r] + bj[0];
          g1 = acc[i][1][r] + bj[1];
          g2 = acc[i][2][r] + bj[2];
          g3 = acc[i][3][r] + bj[3];
        }
        float ig = sigf(g0), fg = sigf(g1), gg = tanh_(g2), og = sigf(g3);
        size_t si = (size_t)row*1024 + u;
        float cn = fg * cst[si] + ig * gg;
        cst[si] = cn;
        float hn = og * tanh_(cn);
        u16 hb = f2bf(hn);
        hout[si] = hb;
        if (MODE == 2) hout2[(size_t)row*32768 + u] = hb;  // feats[b][t][u]
      }
    }
  }
}

// ---- standalone GEMM (MODE 0 prep, MODE 3 head). SWZ: bijective XCD chunking
// so the 8 bx-blocks sharing one A-tile land on ONE XCD's L2 (grid (8,256)).
template<int MODE, int SWZ>
__global__ __launch_bounds__(256)
void gemm_k(const u16* __restrict__ A0, const u16* __restrict__ Bp, int K,
            const float* __restrict__ add, float* __restrict__ outf)
{
  __shared__ __align__(16) u16 sA[3*8192];
  int bx = blockIdx.x, by = blockIdx.y;
  if constexpr (SWZ){
    int lin = by * (int)gridDim.x + bx;   // hw: XCD = lin & 7
    int xcd = lin & 7, idx = lin >> 3;    // idx 0..255 within XCD
    by = xcd*32 + (idx >> 3);             // each XCD: 32 contiguous by-tiles
    bx = idx & 7;
  }
  gemm_core<MODE>(bx, by, A0, nullptr, 1<<20, Bp, K, add,
                  nullptr, nullptr, nullptr, outf, sA);
}

// ---- fused step: L1(t) (blocks by<8) runs concurrently with L0(t+1) (by>=8).
// roles: 0 = both (grid y=16), 1 = L0 only (y=8), 2 = L1 only (y=8).
__global__ __launch_bounds__(256)
void fused_step(const u16* __restrict__ h0in, const u16* __restrict__ h1in,
                const u16* __restrict__ Whh0p, const u16* __restrict__ W1p,
                const float* __restrict__ X0p, const float* __restrict__ B1,
                float* __restrict__ C0, float* __restrict__ C1,
                u16* __restrict__ h0out, u16* __restrict__ h1out,
                u16* __restrict__ feats, int roles)
{
  __shared__ __align__(16) u16 sA[3*8192];
  int by = blockIdx.y, isL0;
  if (roles == 0){ isL0 = (by >= 8); by &= 7; }
  else isL0 = (roles == 1);
  if (isL0)   // h0(next) = cell(X0p, h0in, C0)
    gemm_core<1>(blockIdx.x, by, h0in, nullptr, 1<<20, Whh0p, 1024, X0p,
                 C0, h0out, nullptr, nullptr, sA);
  else        // h1(next) = cell([h0in|h1in]@W1^T + B1, C1); writes feats
    gemm_core<2>(blockIdx.x, by, h0in, h1in, 1024, W1p, 2048, B1,
                 C1, h1out, feats, nullptr, sA);
}

// ---------------------------------------------------------------------------
extern "C" void kernel_launch(void* const* d_in, const int* in_sizes, int n_in,
                              void* d_out, int out_size, void* d_ws, size_t ws_size,
                              hipStream_t stream)
{
  (void)in_sizes; (void)n_in; (void)out_size; (void)ws_size;
  const float* z    = (const float*)d_in[0];
  const float* gam  = (const float*)d_in[1];
  const float* bet  = (const float*)d_in[2];
  const float* Wih0 = (const float*)d_in[3];
  const float* Whh0 = (const float*)d_in[4];
  const float* bih0 = (const float*)d_in[5];
  const float* bhh0 = (const float*)d_in[6];
  const float* Wih1 = (const float*)d_in[7];
  const float* Whh1 = (const float*)d_in[8];
  const float* bih1 = (const float*)d_in[9];
  const float* bhh1 = (const float*)d_in[10];
  const float* Wlin = (const float*)d_in[11];
  const float* blin = (const float*)d_in[12];
  float* out = (float*)d_out;

  char* p = (char*)d_ws;
  auto alloc = [&](size_t b) -> void* { void* r = (void*)p; p += (b + 255) & ~(size_t)255; return r; };
  u16*  Wih0p = (u16*)alloc((size_t)4096*1024*2);   // packed fragment order
  u16*  Whh0p = (u16*)alloc((size_t)4096*1024*2);
  u16*  W1p   = (u16*)alloc((size_t)4096*2048*2);   // [W_ih1 | W_hh1] along K
  u16*  Wlinp = (u16*)alloc((size_t)1024*1024*2);
  float* Bx0  = (float*)alloc(4096*4);
  float* B1   = (float*)alloc(4096*4);
  float* X0p  = (float*)alloc((size_t)1024*4096*4);
  u16*  H0a   = (u16*)alloc((size_t)1024*1024*2);
  u16*  H0b   = (u16*)alloc((size_t)1024*1024*2);
  u16*  H1a   = (u16*)alloc((size_t)1024*1024*2);
  u16*  H1b   = (u16*)alloc((size_t)1024*1024*2);
  float* C0   = (float*)alloc((size_t)1024*1024*4);
  float* C1   = (float*)alloc((size_t)1024*1024*4);
  u16*  Feats = (u16*)alloc((size_t)1024*32*1024*2);
  float* PS   = (float*)alloc(16*1024*4);
  float* PQ   = (float*)alloc(16*1024*4);
  float* Sc   = (float*)alloc(1024*4);
  float* Sh   = (float*)alloc(1024*4);

  // prep
  bn_stats<<<64, 256, 0, stream>>>(z, PS, PQ);
  bn_fin<<<4, 256, 0, stream>>>(PS, PQ, gam, bet, Sc, Sh);
  bn_norm<<<64, 256, 0, stream>>>(z, Sc, Sh, H0a, H1a, C0, C1);
  // packed weights: chunks = (N/128)*(K/64)*16; grid = chunks/4
  pack_w<<<2048, 256, 0, stream>>>(Wih0, Wih0, 1<<20, 1024, 1, Wih0p);
  pack_w<<<2048, 256, 0, stream>>>(Whh0, Whh0, 1<<20, 1024, 1, Whh0p);
  pack_w<<<4096, 256, 0, stream>>>(Wih1, Whh1, 1024, 2048, 1, W1p);
  pack_w<<< 512, 256, 0, stream>>>(Wlin, Wlin, 1<<20, 1024, 0, Wlinp);
  bias_k<<<16, 256, 0, stream>>>(bih0, bhh0, bih1, bhh1, Bx0, B1);

  // x0_proj = zn @ W_ih0p^T + (b_ih0 + b_hh0)   (constant over steps)
  gemm_k<0,0><<<dim3(32,8), 256, 0, stream>>>(H0a, Wih0p, 1024, Bx0, X0p);

  u16* h0b[2] = {H0a, H0b};
  u16* h1b[2] = {H1a, H1b};

  // h0(1) <- h0(0): L0 alone (nothing to overlap with yet)
  fused_step<<<dim3(32,8), 256, 0, stream>>>(h0b[0], nullptr, Whh0p, W1p, X0p, B1,
                                             C0, C1, h0b[1], nullptr, nullptr, 1);
  // steps t=0..30: L1(t) uses h0(t+1); concurrently L0 computes h0(t+2)
  for (int t = 0; t < 31; ++t){
    fused_step<<<dim3(32,16), 256, 0, stream>>>(
        h0b[(t+1)&1], h1b[t&1], Whh0p, W1p, X0p, B1,
        C0, C1, h0b[t&1], h1b[(t+1)&1], Feats + (size_t)t*1024, 0);
  }
  // final L1(31): uses h0(32)=h0b[0], h1 state h1b[1]
  fused_step<<<dim3(32,8), 256, 0, stream>>>(h0b[0], h1b[1], Whh0p, W1p, X0p, B1,
                                             C0, C1, nullptr, h1b[0], Feats + (size_t)31*1024, 2);

  // out = feats @ W_lin^T + b_lin  (XCD-chunked swizzle for A-tile L2 reuse)
  gemm_k<3,1><<<dim3(8,256), 256, 0, stream>>>(Feats, Wlinp, 1024, blin, out);
}